// Round 8
// baseline (749.735 us; speedup 1.0000x reference)
//
#include <hip/hip_runtime.h>
#include <hip/hip_bf16.h>
#include <math.h>

// ---------------- workspace layout (floats) ----------------
#define WS_AT    0            // At fp32 20480 (free region; no overlap with xp)
#define WS_YSUM  20480        // 40
#define WS_XMAX  20520        // 8
#define WS_HIST  20528        // 816 (int)
#define WS_THR   21344        // 32
#define WS_MN    21376        // 40 (uint)
#define WS_MX    21440        // 40 (uint)
#define WS_XP    21504        // 8*3*256*256 = 1572864
#define WS_IA    1594368      // 8*256*256   = 524288
#define WS_XGL   2118656      // 8*256*256   = 524288
// P2 = ws + WS_XP + 20480 (1310720 floats, inside xp region, written after conv7)

#define GDM_OUT  655360       // 8*5*128*128

static __device__ __forceinline__ float xv_val(int i) {
    double t = (double)i / 100.0;
    return (float)(10.0 * t * t * t);
}

// ---- F1: fused [pool3+mean | mixA | zero ysum/hist/xmax] ----
__global__ __launch_bounds__(256) void k_front(const float* __restrict__ x,
                                               const float* __restrict__ hw,
                                               const float* __restrict__ fcw,
                                               float* __restrict__ xp,
                                               float* __restrict__ ia,
                                               float* __restrict__ At,
                                               float* __restrict__ zr) {
    int bid = blockIdx.x;
    if (bid < 2048) {
        int idx = bid * 256 + threadIdx.x;
        int b = idx >> 16; int p = idx & 65535; int oy = p >> 8; int ox = p & 255;
        float cs[3];
#pragma unroll
        for (int c = 0; c < 3; ++c) {
            const float* src = x + (((size_t)(b * 3 + c)) << 18);
            float s = 0.f;
#pragma unroll
            for (int dy = -1; dy <= 1; ++dy) {
                int iy = 2 * oy + dy; if ((unsigned)iy >= 512u) continue;
#pragma unroll
                for (int dx = -1; dx <= 1; ++dx) {
                    int ix = 2 * ox + dx; if ((unsigned)ix >= 512u) continue;
                    s += src[iy * 512 + ix];
                }
            }
            cs[c] = s * (1.f / 9.f);
            xp[(((size_t)(b * 3 + c)) << 16) + p] = cs[c];
        }
        ia[(((size_t)b) << 16) + p] = (cs[0] + cs[1] + cs[2]) * (1.f / 3.f);
    } else if (bid < 2128) {
        // mixA: A[(d*64+c)*64+o] = scale_d * sum_m fc_w[o][d*64+m]*hw[m][c][goff_d]
        int idx = (bid - 2048) * 256 + threadIdx.x;   // 20480
        int o = idx & 63; int k = idx >> 6;           // k = d*64+c
        int d = k >> 6; int c = k & 63;
        const int goff[5] = {0, 1, 2, 3, 8};
        float s = 0.f;
        for (int m = 0; m < 64; ++m)
            s += fcw[o * 320 + d * 64 + m] * hw[(m * 64 + c) * 9 + goff[d]];
        At[k * 64 + o] = s * ((d == 4) ? 4.f : 1.f);
    } else {
        // zero ysum(40) + xmax(8) + hist(816) = 864 floats at zr
#pragma unroll
        for (int q = 0; q < 4; ++q) {
            int i = threadIdx.x + 256 * q;
            if (i < 864) zr[i] = 0.f;
        }
    }
}

// ---- G2: conv7x7 s2 p3, all 5 cos per block (xp read once) ----
__global__ __launch_bounds__(256) void k_conv7(const float* __restrict__ xp,
                                               const float* __restrict__ w,
                                               float* __restrict__ ysum) {
    int b = blockIdx.y;
    int p = blockIdx.x * 256 + threadIdx.x;
    int oy = p >> 7, ox = p & 127;
    __shared__ float wsm[735];
    for (int l = threadIdx.x; l < 735; l += 256) wsm[l] = w[l];
    __syncthreads();
    float s[5] = {0.f, 0.f, 0.f, 0.f, 0.f};
    for (int ic = 0; ic < 3; ++ic) {
        const float* src = xp + (((size_t)(b * 3 + ic)) << 16);
#pragma unroll
        for (int r = 0; r < 7; ++r) {
            int iy = 2 * oy - 3 + r; if ((unsigned)iy >= 256u) continue;
#pragma unroll
            for (int ss = 0; ss < 7; ++ss) {
                int ix = 2 * ox - 3 + ss; if ((unsigned)ix >= 256u) continue;
                float v = src[iy * 256 + ix];
                int wi = (ic * 7 + r) * 7 + ss;
#pragma unroll
                for (int co = 0; co < 5; ++co) s[co] = fmaf(wsm[co * 147 + wi], v, s[co]);
            }
        }
    }
    __shared__ float red[256];
#pragma unroll
    for (int co = 0; co < 5; ++co) {
        red[threadIdx.x] = s[co]; __syncthreads();
        for (int off = 128; off > 0; off >>= 1) {
            if (threadIdx.x < off) red[threadIdx.x] += red[threadIdx.x + off];
            __syncthreads();
        }
        if (threadIdx.x == 0) atomicAdd(&ysum[b * 5 + co], red[0]);
        __syncthreads();
    }
}

// ---- G4: x_GL + histogram + per-b max ----
__global__ __launch_bounds__(256) void k_gl_hist(const float* __restrict__ ia,
                                                 const float* __restrict__ gdmw,
                                                 float* __restrict__ xgl,
                                                 int* __restrict__ hist,
                                                 unsigned* __restrict__ xmax) {
    int b = blockIdx.y;
    int p = blockIdx.x * 256 + threadIdx.x;
    int y = p >> 8, x = p & 255;
    __shared__ float xv[101];
    __shared__ int sh[102];
    __shared__ float redm[256];
    if (threadIdx.x < 101) xv[threadIdx.x] = xv_val(threadIdx.x);
    if (threadIdx.x < 102) sh[threadIdx.x] = 0;
    __syncthreads();
    const float* src = ia + (((size_t)b) << 16);
    float a1 = gdmw[0] * 4.f;
    auto rd = [&](int dy, int dx) -> float {
        int iy = y + dy, ix = x + dx;
        if ((unsigned)iy >= 256u || (unsigned)ix >= 256u) return 0.f;
        return src[iy * 256 + ix];
    };
    float acc = rd(0, 0)
        - 0.125f  * (rd(-1, 0) + rd(0, -1) + rd(0, 1) + rd(1, 0))
        - 0.0625f * (rd(-2, 0) + rd(-1, -1) + rd(-1, 1) + rd(0, -2) +
                     rd(0, 2) + rd(1, -1) + rd(1, 1) + rd(2, 0));
    float raw = fabsf(a1 * acc);
    float val = (raw < 1e-6f) ? 0.f : raw;
    xgl[(((size_t)b) << 16) + p] = val;
    if (val > 0.f) {
        int lo = 0, hi = 101;
        while (lo < hi) { int mid = (lo + hi) >> 1; if (val <= xv[mid]) hi = mid; else lo = mid + 1; }
        atomicAdd(&sh[lo], 1);
    }
    redm[threadIdx.x] = val; __syncthreads();
    for (int off = 128; off > 0; off >>= 1) {
        if (threadIdx.x < off) redm[threadIdx.x] = fmaxf(redm[threadIdx.x], redm[threadIdx.x + off]);
        __syncthreads();
    }
    if (threadIdx.x == 0) atomicMax(&xmax[b], __float_as_uint(redm[0]));
    if (threadIdx.x < 102 && sh[threadIdx.x]) atomicAdd(&hist[b * 102 + threadIdx.x], sh[threadIdx.x]);
}

// ---- G5: thresholds + init pool min/max ----
__global__ void k_thresholds(const float* __restrict__ ysum, const float* __restrict__ gamma,
                             const float* __restrict__ beta, const float* __restrict__ mean,
                             const float* __restrict__ var, const int* __restrict__ hist,
                             float* __restrict__ thr, unsigned* __restrict__ mnb,
                             unsigned* __restrict__ mxb) {
    int b = threadIdx.x;
    if (b >= 8) {
        if (b < 48) { mnb[b - 8] = 0x7f7fffffu; mxb[b - 8] = 0u; }
        return;
    }
    float wa[5];
    for (int c = 1; c < 5; ++c) {
        float m = ysum[b * 5 + c] * (1.f / 16384.f);
        wa[c] = tanhf((m - mean[c]) * rsqrtf(var[c] + 1e-5f) * gamma[c] + beta[c]);
    }
    float pr[4] = {0.2f + 0.05f * wa[1], 0.4f + 0.05f * wa[2],
                   0.6f + 0.05f * wa[3], 0.8f + 0.05f * wa[4]};
    auto sw = [&](int i, int j) { if (pr[i] > pr[j]) { float t = pr[i]; pr[i] = pr[j]; pr[j] = t; } };
    sw(0, 1); sw(2, 3); sw(0, 2); sw(1, 3); sw(1, 2);
    int all = 0;
    for (int i = 0; i <= 101; ++i) all += hist[b * 102 + i];
    float bestz[4] = {1e30f, 1e30f, 1e30f, 1e30f};
    int besti[4] = {0, 0, 0, 0};
    int cum = 0;
    for (int i = 0; i <= 100; ++i) {
        cum += hist[b * 102 + i];
        float pct = (float)cum / (float)all;
        for (int t = 0; t < 4; ++t) {
            float z = fabsf(pct - pr[t]);
            if (z < bestz[t]) { bestz[t] = z; besti[t] = i; }
        }
    }
    for (int t = 0; t < 4; ++t) thr[b * 4 + t] = xv_val(besti[t]);
}

// ---- P1: mask + h-box9 + v-box9 -> p0 [40][256][256] ----
#define F1_STR 268
__global__ __launch_bounds__(256) void k_hv1(const float* __restrict__ in,
                                             const float* __restrict__ thr,
                                             const unsigned* __restrict__ xmax,
                                             float* __restrict__ outp) {
    int plane = blockIdx.y;
    int r0 = blockIdx.x * 8;
    int b = plane / 5, band = plane - 5 * b;
    float tmin = (band == 0) ? 0.f : thr[b * 4 + band - 1];
    float tmax = (band == 4) ? __uint_as_float(xmax[b]) : thr[b * 4 + band];
    const float* src = in + (((size_t)b) << 16);
    __shared__ float mr[16][F1_STR];
    __shared__ float hh[16][256];
    int tid = threadIdx.x;
    for (int l = tid; l < 16 * 256; l += 256) {
        int i = l >> 8, c = l & 255;
        int rr = r0 - 4 + i;
        float v = ((unsigned)rr < 256u) ? src[rr * 256 + c] : 0.f;
        v = (v > tmin && v <= tmax) ? 1.f : 0.f;
        mr[i][c + 4] = v;
    }
    if (tid < 128) { int i = tid >> 3, p = tid & 7; mr[i][p < 4 ? p : 256 + p] = 0.f; }
    __syncthreads();
    {
        int r = tid >> 4, x0 = (tid & 15) * 16;
        float w[24];
#pragma unroll
        for (int k = 0; k < 6; ++k) {
            float4 q = *(const float4*)&mr[r][x0 + 4 * k];
            w[4 * k] = q.x; w[4 * k + 1] = q.y; w[4 * k + 2] = q.z; w[4 * k + 3] = q.w;
        }
        float o[16];
        float s = 0.f;
#pragma unroll
        for (int k = 0; k < 9; ++k) s += w[k];
#pragma unroll
        for (int j = 0; j < 16; ++j) {
            o[j] = s * (1.f / 9.f);
            if (j < 15) s += w[j + 9] - w[j];
        }
#pragma unroll
        for (int k = 0; k < 4; ++k) {
            float4 q = {o[4 * k], o[4 * k + 1], o[4 * k + 2], o[4 * k + 3]};
            *(float4*)&hh[r][x0 + 4 * k] = q;
        }
    }
    __syncthreads();
    {
        int c = tid;
        float ld[16];
#pragma unroll
        for (int i = 0; i < 16; ++i) ld[i] = hh[i][c];
        float s = 0.f;
#pragma unroll
        for (int k = 0; k < 9; ++k) s += ld[k];
        float* dst = outp + (((size_t)plane) << 16);
#pragma unroll
        for (int j = 0; j < 8; ++j) {
            dst[(r0 + j) * 256 + c] = s * (1.f / 9.f);
            if (j < 7) s += ld[j + 9] - ld[j];
        }
    }
}

// ---- P2: fused pass2 (h+v) + pass3 (h_s2+v_s2) + minmax: p0 -> P2[40][128][128] ----
__global__ __launch_bounds__(256) void k_hv2s2(const float* __restrict__ in,
                                               float* __restrict__ outp,
                                               unsigned* __restrict__ mnb,
                                               unsigned* __restrict__ mxb) {
    int plane = blockIdx.y;
    int r0 = blockIdx.x * 8;              // final output rows r0..r0+7 (of 128)
    __shared__ float mr[31][264];
    __shared__ float hh[31][256];
    int tid = threadIdx.x;
    const float* src = in + (((size_t)plane) << 16);
    for (int l = tid; l < 31 * 264; l += 256) {
        int i = l / 264, c = l - i * 264;
        int rr = 2 * r0 - 8 + i, cc = c - 4;
        mr[i][c] = ((unsigned)rr < 256u && (unsigned)cc < 256u) ? src[rr * 256 + cc] : 0.f;
    }
    __syncthreads();
    for (int l = tid; l < 31 * 256; l += 256) {
        int i = l >> 8, x = l & 255;
        float s = 0.f;
#pragma unroll
        for (int k = 0; k < 9; ++k) s += mr[i][x + k];
        hh[i][x] = s * (1.f / 9.f);
    }
    __syncthreads();
    for (int l = tid; l < 23 * 256; l += 256) {
        int i2 = l >> 8, x = l & 255;
        float s = 0.f;
#pragma unroll
        for (int k = 0; k < 9; ++k) s += hh[i2 + k][x];
        float v = s * (1.f / 9.f);
        if ((unsigned)(2 * r0 - 4 + i2) >= 256u) v = 0.f;
        mr[i2][x + 4] = v;
    }
    if (tid < 184) { int i2 = tid / 8, p = tid & 7; mr[i2][p < 4 ? p : 256 + p] = 0.f; }
    __syncthreads();
    for (int l = tid; l < 23 * 128; l += 256) {
        int i2 = l >> 7, ox = l & 127;
        float s = 0.f;
#pragma unroll
        for (int k = 0; k < 9; ++k) s += mr[i2][2 * ox + k];
        hh[i2][ox] = s * (1.f / 9.f);
    }
    __syncthreads();
    float vmn = 1e30f, vmx = -1e30f;
    float* dst = outp + (size_t)plane * 16384;
#pragma unroll
    for (int q = 0; q < 4; ++q) {
        int l = tid + 256 * q;
        int jj = l >> 7, ox = l & 127;
        float s = 0.f;
#pragma unroll
        for (int k = 0; k < 9; ++k) s += hh[2 * jj + k][ox];
        s *= (1.f / 9.f);
        dst[(r0 + jj) * 128 + ox] = s;
        vmn = fminf(vmn, s); vmx = fmaxf(vmx, s);
    }
    __syncthreads();
    float* smn = &hh[23][0];
    float* smx = &hh[24][0];
    smn[tid] = vmn; smx[tid] = vmx; __syncthreads();
    for (int off = 128; off > 0; off >>= 1) {
        if (tid < off) {
            smn[tid] = fminf(smn[tid], smn[tid + off]);
            smx[tid] = fmaxf(smx[tid], smx[tid + off]);
        }
        __syncthreads();
    }
    if (tid == 0) {
        atomicMin(&mnb[plane], __float_as_uint(smn[0]));
        atomicMax(&mxb[plane], __float_as_uint(smx[0]));
    }
}

// ---- normalize ----
__global__ __launch_bounds__(256) void k_norm(const float* __restrict__ in,
                                              const unsigned* __restrict__ mnb,
                                              const unsigned* __restrict__ mxb,
                                              float* __restrict__ gdm) {
    int i4 = blockIdx.x * 256 + threadIdx.x;
    int idx = i4 * 4;
    int plane = idx >> 14;
    float mn = __uint_as_float(mnb[plane]), mx = __uint_as_float(mxb[plane]);
    float inv = 1.f / (mx - mn);
    float4 v = *(const float4*)&in[idx];
    float4 o = {(v.x - mn) * inv, (v.y - mn) * inv, (v.z - mn) * inv, (v.w - mn) * inv};
    *(float4*)&gdm[idx] = o;
}

// ---- H2: 512-thread blocks; two 256-thread wave-groups K-split (grp*32..+31),
//      r2-verified per-group pipeline, intra-block LDS merge (no atomics) ----
__global__ __launch_bounds__(512, 4) void k_hge(const float* __restrict__ feat,
                                                const float* __restrict__ At,
                                                const float* __restrict__ fcb,
                                                float* __restrict__ out) {
    int tile = blockIdx.x, b = blockIdx.y;
    int ty = (tile >> 3) * 16, tx = (tile & 7) * 16;
    int tid = threadIdx.x;
    int grp = tid >> 8, tg = tid & 255;
    int zbase = grp * 32;
    __shared__ float ft[2][2][20][21];      // [grp][ch][r][c]   6720 B
    __shared__ float tl[2][2][5][256];      // [grp][ch][d][px] 20480 B (single-buffered: safe,
                                            //  stencil(g+1) writes only after post-FMA(g) barrier)
    __shared__ float al[2][2][2][5][64];    // [buf][grp][ch][d][o] 10240 B
    int og = tg >> 5, pg = tg & 31;
    float acc[8][8];                        // [pj][oi], px = pg + 32*pj
#pragma unroll
    for (int i = 0; i < 8; ++i)
#pragma unroll
        for (int j = 0; j < 8; ++j) acc[i][j] = 0.f;

    const float* cur[6];
    int str[6];
    bool ok[6];
#pragma unroll
    for (int j = 0; j < 6; ++j) {
        int l = tg + 256 * j;
        cur[j] = nullptr; str[j] = 0; ok[j] = false;
        if (l < 800) {
            int ch = (l >= 400); int rem = l - ch * 400;
            int r = rem / 20, cx = rem - r * 20;
            int gy = ty - 2 + r, gx = tx - 2 + cx;
            if ((unsigned)gy < 128u && (unsigned)gx < 128u) {
                cur[j] = feat + (((size_t)(b * 64 + zbase + ch)) << 14) + gy * 128 + gx;
                str[j] = 2 << 14;
                ok[j] = true;
            }
        } else if (l < 1440) {
            int q = l - 800;
            int ch = (q >= 320); int k = q - ch * 320;   // d*64+o
            cur[j] = At + ((k >> 6) * 64 + zbase + ch) * 64 + (k & 63);
            str[j] = 128;
            ok[j] = true;
        }
    }
    float pr[6];
#pragma unroll
    for (int j = 0; j < 6; ++j) pr[j] = ok[j] ? *cur[j] : 0.f;

    int py = tg >> 4, px = tg & 15;
    for (int g = 0; g < 16; ++g) {
        int buf = g & 1;
#pragma unroll
        for (int j = 0; j < 6; ++j) {
            int l = tg + 256 * j;
            if (l < 800) {
                int ch = (l >= 400); int rem = l - ch * 400;
                int r = rem / 20, cx = rem - r * 20;
                ft[grp][ch][r][cx] = pr[j];
            } else if (l < 1440) {
                ((float*)al[buf][grp])[l - 800] = pr[j];
            }
        }
        __syncthreads();
        if (g < 15) {
#pragma unroll
            for (int j = 0; j < 6; ++j) {
                if (ok[j]) { cur[j] += str[j]; pr[j] = *cur[j]; }
            }
        }
        {
            int cy = py + 2, cx = px + 2;
#pragma unroll
            for (int ch = 0; ch < 2; ++ch) {
                float fm2 = ft[grp][ch][cy - 2][cx], f2p = ft[grp][ch][cy + 2][cx];
                float fl2 = ft[grp][ch][cy][cx - 2], fr2 = ft[grp][ch][cy][cx + 2];
                float a  = ft[grp][ch][cy - 1][cx - 1], bq = ft[grp][ch][cy - 1][cx], cc = ft[grp][ch][cy - 1][cx + 1];
                float dd = ft[grp][ch][cy][cx - 1],     ee = ft[grp][ch][cy][cx],     ffv = ft[grp][ch][cy][cx + 1];
                float g_ = ft[grp][ch][cy + 1][cx - 1], h  = ft[grp][ch][cy + 1][cx], i2 = ft[grp][ch][cy + 1][cx + 1];
                tl[grp][ch][0][tg] = (a + 2.f * bq + cc) - (g_ + 2.f * h + i2);
                tl[grp][ch][1][tg] = 2.f * a + bq + dd - ffv - h - 2.f * i2;
                tl[grp][ch][2][tg] = (a - cc) + 2.f * (dd - ffv) + (g_ - i2);
                tl[grp][ch][3][tg] = -bq - 2.f * cc + dd - ffv + 2.f * g_ + h;
                tl[grp][ch][4][tg] = ee - 0.125f * (bq + dd + ffv + h)
                                   - 0.0625f * (fm2 + a + cc + fl2 + fr2 + g_ + i2 + f2p);
            }
        }
        __syncthreads();
        // FMA: tv scalar broadcast reads (lane-stride-1, conflict-free; r1-verified mapping)
#pragma unroll
        for (int ch = 0; ch < 2; ++ch) {
#pragma unroll
            for (int d = 0; d < 5; ++d) {
                float4 a0 = *(const float4*)&al[buf][grp][ch][d][og * 8];
                float4 a1 = *(const float4*)&al[buf][grp][ch][d][og * 8 + 4];
                float av[8] = {a0.x, a0.y, a0.z, a0.w, a1.x, a1.y, a1.z, a1.w};
#pragma unroll
                for (int pj = 0; pj < 8; ++pj) {
                    float tv = tl[grp][ch][d][pg + 32 * pj];
#pragma unroll
                    for (int oi = 0; oi < 8; ++oi)
                        acc[pj][oi] = fmaf(av[oi], tv, acc[pj][oi]);
                }
            }
        }
    }
    // intra-block merge: grp1 -> LDS (tl region, conflict-free f*256+tg), grp0 accumulates
    __syncthreads();
    float* mrg = &tl[0][0][0][0];           // 5120 floats available, 4096 used per chunk
#pragma unroll
    for (int c = 0; c < 4; ++c) {
        if (grp == 1) {
#pragma unroll
            for (int f = 0; f < 16; ++f) mrg[f * 256 + tg] = acc[c * 2 + (f >> 3)][f & 7];
        }
        __syncthreads();
        if (grp == 0) {
#pragma unroll
            for (int f = 0; f < 16; ++f) acc[c * 2 + (f >> 3)][f & 7] += mrg[f * 256 + tg];
        }
        __syncthreads();
    }
    if (grp == 0) {
#pragma unroll
        for (int oi = 0; oi < 8; ++oi) {
            int o = og * 8 + oi;
            float bias = fcb[o];
            float* dsto = out + (((size_t)(b * 64 + o)) << 14);
#pragma unroll
            for (int pj = 0; pj < 8; ++pj) {
                int pxl = pg + 32 * pj;
                dsto[(ty + (pxl >> 4)) * 128 + tx + (pxl & 15)] = acc[pj][oi] + bias;
            }
        }
    }
}

extern "C" void kernel_launch(void* const* d_in, const int* in_sizes, int n_in,
                              void* d_out, int out_size, void* d_ws, size_t ws_size,
                              hipStream_t stream) {
    const float* x    = (const float*)d_in[0];
    const float* gdmw = (const float*)d_in[1];
    const float* convw= (const float*)d_in[2];
    const float* bng  = (const float*)d_in[3];
    const float* bnb  = (const float*)d_in[4];
    const float* bnm  = (const float*)d_in[5];
    const float* bnv  = (const float*)d_in[6];
    const float* feat = (const float*)d_in[7];
    const float* hw   = (const float*)d_in[8];
    const float* fcw  = (const float*)d_in[9];
    const float* fcb  = (const float*)d_in[10];
    float* out = (float*)d_out;
    float* ws  = (float*)d_ws;

    float* At   = ws + WS_AT;            // dedicated region: no xp overlap (fixes r6 race)
    float* ysum = ws + WS_YSUM;
    unsigned* xmax = (unsigned*)(ws + WS_XMAX);
    int* hist   = (int*)(ws + WS_HIST);
    float* thr  = ws + WS_THR;
    unsigned* mnb = (unsigned*)(ws + WS_MN);
    unsigned* mxb = (unsigned*)(ws + WS_MX);
    float* xp   = ws + WS_XP;
    float* ia   = ws + WS_IA;
    float* xgl  = ws + WS_XGL;
    float* p2   = ws + WS_XP + 20480;    // written by hv2s2 (after conv7 consumed xp)

    float* hge = out + GDM_OUT;
    float* p0  = hge;                    // [40][256][256] in hge region (overwritten by k_hge)

    k_front      <<<2129, 256, 0, stream>>>(x, hw, fcw, xp, ia, At, ws + WS_YSUM);
    k_conv7      <<<dim3(64, 8), 256, 0, stream>>>(xp, convw, ysum);
    k_gl_hist    <<<dim3(256, 8), 256, 0, stream>>>(ia, gdmw, xgl, hist, xmax);
    k_thresholds <<<1, 64, 0, stream>>>(ysum, bng, bnb, bnm, bnv, hist, thr, mnb, mxb);
    k_hv1        <<<dim3(32, 40), 256, 0, stream>>>(xgl, thr, xmax, p0);
    k_hv2s2      <<<dim3(16, 40), 256, 0, stream>>>(p0, p2, mnb, mxb);
    k_norm       <<<640, 256, 0, stream>>>(p2, mnb, mxb, out);
    k_hge        <<<dim3(64, 8), 512, 0, stream>>>(feat, At, fcb, hge);
}

// Round 9
// 250.385 us; speedup vs baseline: 2.9943x; 2.9943x over previous
//
#include <hip/hip_runtime.h>
#include <hip/hip_bf16.h>
#include <math.h>

// ---------------- workspace layout (floats) ----------------
#define WS_AT    0            // At fp32 20480 (dedicated; no overlap)
#define WS_YSUM  20480        // 40
#define WS_XMAX  20520        // 8
#define WS_HIST  20528        // 816 (int)
#define WS_THR   21344        // 32
#define WS_MN    21376        // 40 (uint)
#define WS_MX    21440        // 40 (uint)
#define WS_XP    21504        // 8*3*256*256 = 1572864
#define WS_IA    1594368      // 8*256*256   = 524288
#define WS_XGL   2118656      // 8*256*256   = 524288
// P2 = ws + WS_XP + 20480 (1310720 floats, inside xp region, written after conv7)

#define GDM_OUT  655360       // 8*5*128*128

static __device__ __forceinline__ float xv_val(int i) {
    double t = (double)i / 100.0;
    return (float)(10.0 * t * t * t);
}

// ---- F1: fused [pool3+mean | mixA | zero ysum/hist/xmax] ----
__global__ __launch_bounds__(256) void k_front(const float* __restrict__ x,
                                               const float* __restrict__ hw,
                                               const float* __restrict__ fcw,
                                               float* __restrict__ xp,
                                               float* __restrict__ ia,
                                               float* __restrict__ At,
                                               float* __restrict__ zr) {
    int bid = blockIdx.x;
    if (bid < 2048) {
        int idx = bid * 256 + threadIdx.x;
        int b = idx >> 16; int p = idx & 65535; int oy = p >> 8; int ox = p & 255;
        float cs[3];
#pragma unroll
        for (int c = 0; c < 3; ++c) {
            const float* src = x + (((size_t)(b * 3 + c)) << 18);
            float s = 0.f;
#pragma unroll
            for (int dy = -1; dy <= 1; ++dy) {
                int iy = 2 * oy + dy; if ((unsigned)iy >= 512u) continue;
#pragma unroll
                for (int dx = -1; dx <= 1; ++dx) {
                    int ix = 2 * ox + dx; if ((unsigned)ix >= 512u) continue;
                    s += src[iy * 512 + ix];
                }
            }
            cs[c] = s * (1.f / 9.f);
            xp[(((size_t)(b * 3 + c)) << 16) + p] = cs[c];
        }
        ia[(((size_t)b) << 16) + p] = (cs[0] + cs[1] + cs[2]) * (1.f / 3.f);
    } else if (bid < 2128) {
        int idx = (bid - 2048) * 256 + threadIdx.x;   // 20480
        int o = idx & 63; int k = idx >> 6;           // k = d*64+c
        int d = k >> 6; int c = k & 63;
        const int goff[5] = {0, 1, 2, 3, 8};
        float s = 0.f;
        for (int m = 0; m < 64; ++m)
            s += fcw[o * 320 + d * 64 + m] * hw[(m * 64 + c) * 9 + goff[d]];
        At[k * 64 + o] = s * ((d == 4) ? 4.f : 1.f);
    } else {
#pragma unroll
        for (int q = 0; q < 4; ++q) {
            int i = threadIdx.x + 256 * q;
            if (i < 864) zr[i] = 0.f;
        }
    }
}

// ---- G2: conv7x7 s2 p3, all 5 cos per block ----
__global__ __launch_bounds__(256) void k_conv7(const float* __restrict__ xp,
                                               const float* __restrict__ w,
                                               float* __restrict__ ysum) {
    int b = blockIdx.y;
    int p = blockIdx.x * 256 + threadIdx.x;
    int oy = p >> 7, ox = p & 127;
    __shared__ float wsm[735];
    for (int l = threadIdx.x; l < 735; l += 256) wsm[l] = w[l];
    __syncthreads();
    float s[5] = {0.f, 0.f, 0.f, 0.f, 0.f};
    for (int ic = 0; ic < 3; ++ic) {
        const float* src = xp + (((size_t)(b * 3 + ic)) << 16);
#pragma unroll
        for (int r = 0; r < 7; ++r) {
            int iy = 2 * oy - 3 + r; if ((unsigned)iy >= 256u) continue;
#pragma unroll
            for (int ss = 0; ss < 7; ++ss) {
                int ix = 2 * ox - 3 + ss; if ((unsigned)ix >= 256u) continue;
                float v = src[iy * 256 + ix];
                int wi = (ic * 7 + r) * 7 + ss;
#pragma unroll
                for (int co = 0; co < 5; ++co) s[co] = fmaf(wsm[co * 147 + wi], v, s[co]);
            }
        }
    }
    __shared__ float red[256];
#pragma unroll
    for (int co = 0; co < 5; ++co) {
        red[threadIdx.x] = s[co]; __syncthreads();
        for (int off = 128; off > 0; off >>= 1) {
            if (threadIdx.x < off) red[threadIdx.x] += red[threadIdx.x + off];
            __syncthreads();
        }
        if (threadIdx.x == 0) atomicAdd(&ysum[b * 5 + co], red[0]);
        __syncthreads();
    }
}

// ---- G4: x_GL + histogram + per-b max ----
__global__ __launch_bounds__(256) void k_gl_hist(const float* __restrict__ ia,
                                                 const float* __restrict__ gdmw,
                                                 float* __restrict__ xgl,
                                                 int* __restrict__ hist,
                                                 unsigned* __restrict__ xmax) {
    int b = blockIdx.y;
    int p = blockIdx.x * 256 + threadIdx.x;
    int y = p >> 8, x = p & 255;
    __shared__ float xv[101];
    __shared__ int sh[102];
    __shared__ float redm[256];
    if (threadIdx.x < 101) xv[threadIdx.x] = xv_val(threadIdx.x);
    if (threadIdx.x < 102) sh[threadIdx.x] = 0;
    __syncthreads();
    const float* src = ia + (((size_t)b) << 16);
    float a1 = gdmw[0] * 4.f;
    auto rd = [&](int dy, int dx) -> float {
        int iy = y + dy, ix = x + dx;
        if ((unsigned)iy >= 256u || (unsigned)ix >= 256u) return 0.f;
        return src[iy * 256 + ix];
    };
    float acc = rd(0, 0)
        - 0.125f  * (rd(-1, 0) + rd(0, -1) + rd(0, 1) + rd(1, 0))
        - 0.0625f * (rd(-2, 0) + rd(-1, -1) + rd(-1, 1) + rd(0, -2) +
                     rd(0, 2) + rd(1, -1) + rd(1, 1) + rd(2, 0));
    float raw = fabsf(a1 * acc);
    float val = (raw < 1e-6f) ? 0.f : raw;
    xgl[(((size_t)b) << 16) + p] = val;
    if (val > 0.f) {
        int lo = 0, hi = 101;
        while (lo < hi) { int mid = (lo + hi) >> 1; if (val <= xv[mid]) hi = mid; else lo = mid + 1; }
        atomicAdd(&sh[lo], 1);
    }
    redm[threadIdx.x] = val; __syncthreads();
    for (int off = 128; off > 0; off >>= 1) {
        if (threadIdx.x < off) redm[threadIdx.x] = fmaxf(redm[threadIdx.x], redm[threadIdx.x + off]);
        __syncthreads();
    }
    if (threadIdx.x == 0) atomicMax(&xmax[b], __float_as_uint(redm[0]));
    if (threadIdx.x < 102 && sh[threadIdx.x]) atomicAdd(&hist[b * 102 + threadIdx.x], sh[threadIdx.x]);
}

// ---- G5: thresholds + init pool min/max ----
__global__ void k_thresholds(const float* __restrict__ ysum, const float* __restrict__ gamma,
                             const float* __restrict__ beta, const float* __restrict__ mean,
                             const float* __restrict__ var, const int* __restrict__ hist,
                             float* __restrict__ thr, unsigned* __restrict__ mnb,
                             unsigned* __restrict__ mxb) {
    int b = threadIdx.x;
    if (b >= 8) {
        if (b < 48) { mnb[b - 8] = 0x7f7fffffu; mxb[b - 8] = 0u; }
        return;
    }
    float wa[5];
    for (int c = 1; c < 5; ++c) {
        float m = ysum[b * 5 + c] * (1.f / 16384.f);
        wa[c] = tanhf((m - mean[c]) * rsqrtf(var[c] + 1e-5f) * gamma[c] + beta[c]);
    }
    float pr[4] = {0.2f + 0.05f * wa[1], 0.4f + 0.05f * wa[2],
                   0.6f + 0.05f * wa[3], 0.8f + 0.05f * wa[4]};
    auto sw = [&](int i, int j) { if (pr[i] > pr[j]) { float t = pr[i]; pr[i] = pr[j]; pr[j] = t; } };
    sw(0, 1); sw(2, 3); sw(0, 2); sw(1, 3); sw(1, 2);
    int all = 0;
    for (int i = 0; i <= 101; ++i) all += hist[b * 102 + i];
    float bestz[4] = {1e30f, 1e30f, 1e30f, 1e30f};
    int besti[4] = {0, 0, 0, 0};
    int cum = 0;
    for (int i = 0; i <= 100; ++i) {
        cum += hist[b * 102 + i];
        float pct = (float)cum / (float)all;
        for (int t = 0; t < 4; ++t) {
            float z = fabsf(pct - pr[t]);
            if (z < bestz[t]) { bestz[t] = z; besti[t] = i; }
        }
    }
    for (int t = 0; t < 4; ++t) thr[b * 4 + t] = xv_val(besti[t]);
}

// ---- P1: mask + h-box9 + v-box9 -> p0 [40][256][256] ----
#define F1_STR 268
__global__ __launch_bounds__(256) void k_hv1(const float* __restrict__ in,
                                             const float* __restrict__ thr,
                                             const unsigned* __restrict__ xmax,
                                             float* __restrict__ outp) {
    int plane = blockIdx.y;
    int r0 = blockIdx.x * 8;
    int b = plane / 5, band = plane - 5 * b;
    float tmin = (band == 0) ? 0.f : thr[b * 4 + band - 1];
    float tmax = (band == 4) ? __uint_as_float(xmax[b]) : thr[b * 4 + band];
    const float* src = in + (((size_t)b) << 16);
    __shared__ float mr[16][F1_STR];
    __shared__ float hh[16][256];
    int tid = threadIdx.x;
    for (int l = tid; l < 16 * 256; l += 256) {
        int i = l >> 8, c = l & 255;
        int rr = r0 - 4 + i;
        float v = ((unsigned)rr < 256u) ? src[rr * 256 + c] : 0.f;
        v = (v > tmin && v <= tmax) ? 1.f : 0.f;
        mr[i][c + 4] = v;
    }
    if (tid < 128) { int i = tid >> 3, p = tid & 7; mr[i][p < 4 ? p : 256 + p] = 0.f; }
    __syncthreads();
    {
        int r = tid >> 4, x0 = (tid & 15) * 16;
        float w[24];
#pragma unroll
        for (int k = 0; k < 6; ++k) {
            float4 q = *(const float4*)&mr[r][x0 + 4 * k];
            w[4 * k] = q.x; w[4 * k + 1] = q.y; w[4 * k + 2] = q.z; w[4 * k + 3] = q.w;
        }
        float o[16];
        float s = 0.f;
#pragma unroll
        for (int k = 0; k < 9; ++k) s += w[k];
#pragma unroll
        for (int j = 0; j < 16; ++j) {
            o[j] = s * (1.f / 9.f);
            if (j < 15) s += w[j + 9] - w[j];
        }
#pragma unroll
        for (int k = 0; k < 4; ++k) {
            float4 q = {o[4 * k], o[4 * k + 1], o[4 * k + 2], o[4 * k + 3]};
            *(float4*)&hh[r][x0 + 4 * k] = q;
        }
    }
    __syncthreads();
    {
        int c = tid;
        float ld[16];
#pragma unroll
        for (int i = 0; i < 16; ++i) ld[i] = hh[i][c];
        float s = 0.f;
#pragma unroll
        for (int k = 0; k < 9; ++k) s += ld[k];
        float* dst = outp + (((size_t)plane) << 16);
#pragma unroll
        for (int j = 0; j < 8; ++j) {
            dst[(r0 + j) * 256 + c] = s * (1.f / 9.f);
            if (j < 7) s += ld[j + 9] - ld[j];
        }
    }
}

// ---- P2: fused pass2 (h+v) + pass3 (h_s2+v_s2) + minmax ----
__global__ __launch_bounds__(256) void k_hv2s2(const float* __restrict__ in,
                                               float* __restrict__ outp,
                                               unsigned* __restrict__ mnb,
                                               unsigned* __restrict__ mxb) {
    int plane = blockIdx.y;
    int r0 = blockIdx.x * 8;
    __shared__ float mr[31][264];
    __shared__ float hh[31][256];
    int tid = threadIdx.x;
    const float* src = in + (((size_t)plane) << 16);
    for (int l = tid; l < 31 * 264; l += 256) {
        int i = l / 264, c = l - i * 264;
        int rr = 2 * r0 - 8 + i, cc = c - 4;
        mr[i][c] = ((unsigned)rr < 256u && (unsigned)cc < 256u) ? src[rr * 256 + cc] : 0.f;
    }
    __syncthreads();
    for (int l = tid; l < 31 * 256; l += 256) {
        int i = l >> 8, x = l & 255;
        float s = 0.f;
#pragma unroll
        for (int k = 0; k < 9; ++k) s += mr[i][x + k];
        hh[i][x] = s * (1.f / 9.f);
    }
    __syncthreads();
    for (int l = tid; l < 23 * 256; l += 256) {
        int i2 = l >> 8, x = l & 255;
        float s = 0.f;
#pragma unroll
        for (int k = 0; k < 9; ++k) s += hh[i2 + k][x];
        float v = s * (1.f / 9.f);
        if ((unsigned)(2 * r0 - 4 + i2) >= 256u) v = 0.f;
        mr[i2][x + 4] = v;
    }
    if (tid < 184) { int i2 = tid / 8, p = tid & 7; mr[i2][p < 4 ? p : 256 + p] = 0.f; }
    __syncthreads();
    for (int l = tid; l < 23 * 128; l += 256) {
        int i2 = l >> 7, ox = l & 127;
        float s = 0.f;
#pragma unroll
        for (int k = 0; k < 9; ++k) s += mr[i2][2 * ox + k];
        hh[i2][ox] = s * (1.f / 9.f);
    }
    __syncthreads();
    float vmn = 1e30f, vmx = -1e30f;
    float* dst = outp + (size_t)plane * 16384;
#pragma unroll
    for (int q = 0; q < 4; ++q) {
        int l = tid + 256 * q;
        int jj = l >> 7, ox = l & 127;
        float s = 0.f;
#pragma unroll
        for (int k = 0; k < 9; ++k) s += hh[2 * jj + k][ox];
        s *= (1.f / 9.f);
        dst[(r0 + jj) * 128 + ox] = s;
        vmn = fminf(vmn, s); vmx = fmaxf(vmx, s);
    }
    __syncthreads();
    float* smn = &hh[23][0];
    float* smx = &hh[24][0];
    smn[tid] = vmn; smx[tid] = vmx; __syncthreads();
    for (int off = 128; off > 0; off >>= 1) {
        if (tid < off) {
            smn[tid] = fminf(smn[tid], smn[tid + off]);
            smx[tid] = fmaxf(smx[tid], smx[tid + off]);
        }
        __syncthreads();
    }
    if (tid == 0) {
        atomicMin(&mnb[plane], __float_as_uint(smn[0]));
        atomicMax(&mxb[plane], __float_as_uint(smx[0]));
    }
}

// ---- normalize ----
__global__ __launch_bounds__(256) void k_norm(const float* __restrict__ in,
                                              const unsigned* __restrict__ mnb,
                                              const unsigned* __restrict__ mxb,
                                              float* __restrict__ gdm) {
    int i4 = blockIdx.x * 256 + threadIdx.x;
    int idx = i4 * 4;
    int plane = idx >> 14;
    float mn = __uint_as_float(mnb[plane]), mx = __uint_as_float(mxb[plane]);
    float inv = 1.f / (mx - mn);
    float4 v = *(const float4*)&in[idx];
    float4 o = {(v.x - mn) * inv, (v.y - mn) * inv, (v.z - mn) * inv, (v.w - mn) * inv};
    *(float4*)&gdm[idx] = o;
}

// ---- H2: 512 threads, OUTPUT-split (grp = o-half), shared ft/tl staging & stencil,
//      acc[8][4] = 32 VGPR per thread, no merge, no atomics ----
__global__ __launch_bounds__(512, 2) void k_hge(const float* __restrict__ feat,
                                                const float* __restrict__ At,
                                                const float* __restrict__ fcb,
                                                float* __restrict__ out) {
    int tile = blockIdx.x, b = blockIdx.y;
    int ty = (tile >> 3) * 16, tx = (tile & 7) * 16;
    int tid = threadIdx.x;
    int grp = tid >> 8, tg = tid & 255;     // grp: output half (o = grp*32 + ...)
    __shared__ float ft[2][20][21];         // [ch][r][c]        3360 B (single buf)
    __shared__ float tl[2][5][256];         // [ch][d][px]      10240 B (single buf; barrier-safe)
    __shared__ float al[2][2][5][64];       // [buf][ch][d][o]  10240 B (full o range)
    int og = tg >> 5, pg = tg & 31;
    float acc[8][4];                        // [pj][oi], px = pg + 32*pj, o = grp*32 + og*4 + oi
#pragma unroll
    for (int i = 0; i < 8; ++i)
#pragma unroll
        for (int j = 0; j < 4; ++j) acc[i][j] = 0.f;

    // staging: 800 ft (2ch x 20x20) + 640 al (2ch x 5 x 64o) = 1440 items over 512 threads
    const float* cur[3];
    int str[3];
    bool ok[3];
#pragma unroll
    for (int j = 0; j < 3; ++j) {
        int l = tid + 512 * j;
        cur[j] = nullptr; str[j] = 0; ok[j] = false;
        if (l < 800) {
            int ch = (l >= 400); int rem = l - ch * 400;
            int r = rem / 20, cx = rem - r * 20;
            int gy = ty - 2 + r, gx = tx - 2 + cx;
            if ((unsigned)gy < 128u && (unsigned)gx < 128u) {
                cur[j] = feat + (((size_t)(b * 64 + ch)) << 14) + gy * 128 + gx;
                str[j] = 2 << 14;            // +2 channels per iteration
                ok[j] = true;
            }
        } else if (l < 1440) {
            int q = l - 800;
            int ch = (q >= 320); int k = q - ch * 320;   // k = d*64+o
            cur[j] = At + (k >> 6) * 4096 + ch * 64 + (k & 63);  // (d*64+c)*64+o, c=ch
            str[j] = 128;                    // c += 2
            ok[j] = true;
        }
    }
    float pr[3];
#pragma unroll
    for (int j = 0; j < 3; ++j) pr[j] = ok[j] ? *cur[j] : 0.f;

    for (int g = 0; g < 32; ++g) {
        int buf = g & 1;
#pragma unroll
        for (int j = 0; j < 3; ++j) {
            int l = tid + 512 * j;
            if (l < 800) {
                int ch = (l >= 400); int rem = l - ch * 400;
                int r = rem / 20, cx = rem - r * 20;
                ft[ch][r][cx] = pr[j];
            } else if (l < 1440) {
                ((float*)al[buf])[l - 800] = pr[j];
            }
        }
        __syncthreads();
        if (g < 31) {
#pragma unroll
            for (int j = 0; j < 3; ++j) {
                if (ok[j]) { cur[j] += str[j]; pr[j] = *cur[j]; }
            }
        }
        // stencil: each of 512 threads does ONE item (px = tg, ch = grp)
        {
            int cy = (tg >> 4) + 2, cx = (tg & 15) + 2;
            int ch = grp;
            float fm2 = ft[ch][cy - 2][cx], f2p = ft[ch][cy + 2][cx];
            float fl2 = ft[ch][cy][cx - 2], fr2 = ft[ch][cy][cx + 2];
            float a  = ft[ch][cy - 1][cx - 1], bq = ft[ch][cy - 1][cx], cc = ft[ch][cy - 1][cx + 1];
            float dd = ft[ch][cy][cx - 1],     ee = ft[ch][cy][cx],     ffv = ft[ch][cy][cx + 1];
            float g_ = ft[ch][cy + 1][cx - 1], h  = ft[ch][cy + 1][cx], i2 = ft[ch][cy + 1][cx + 1];
            tl[ch][0][tg] = (a + 2.f * bq + cc) - (g_ + 2.f * h + i2);
            tl[ch][1][tg] = 2.f * a + bq + dd - ffv - h - 2.f * i2;
            tl[ch][2][tg] = (a - cc) + 2.f * (dd - ffv) + (g_ - i2);
            tl[ch][3][tg] = -bq - 2.f * cc + dd - ffv + 2.f * g_ + h;
            tl[ch][4][tg] = ee - 0.125f * (bq + dd + ffv + h)
                          - 0.0625f * (fm2 + a + cc + fl2 + fr2 + g_ + i2 + f2p);
        }
        __syncthreads();
        // FMA: 8 px (pg+32*pj) x 4 outs (grp*32 + og*4 + oi)
#pragma unroll
        for (int ch = 0; ch < 2; ++ch) {
#pragma unroll
            for (int d = 0; d < 5; ++d) {
                float4 a0 = *(const float4*)&al[buf][ch][d][grp * 32 + og * 4];
                float av[4] = {a0.x, a0.y, a0.z, a0.w};
#pragma unroll
                for (int pj = 0; pj < 8; ++pj) {
                    float tv = tl[ch][d][pg + 32 * pj];
#pragma unroll
                    for (int oi = 0; oi < 4; ++oi)
                        acc[pj][oi] = fmaf(av[oi], tv, acc[pj][oi]);
                }
            }
        }
    }
    // epilogue: plain stores, each thread owns its (o, px) set
#pragma unroll
    for (int oi = 0; oi < 4; ++oi) {
        int o = grp * 32 + og * 4 + oi;
        float bias = fcb[o];
        float* dsto = out + (((size_t)(b * 64 + o)) << 14);
#pragma unroll
        for (int pj = 0; pj < 8; ++pj) {
            int pxl = pg + 32 * pj;
            dsto[(ty + (pxl >> 4)) * 128 + tx + (pxl & 15)] = acc[pj][oi] + bias;
        }
    }
}

extern "C" void kernel_launch(void* const* d_in, const int* in_sizes, int n_in,
                              void* d_out, int out_size, void* d_ws, size_t ws_size,
                              hipStream_t stream) {
    const float* x    = (const float*)d_in[0];
    const float* gdmw = (const float*)d_in[1];
    const float* convw= (const float*)d_in[2];
    const float* bng  = (const float*)d_in[3];
    const float* bnb  = (const float*)d_in[4];
    const float* bnm  = (const float*)d_in[5];
    const float* bnv  = (const float*)d_in[6];
    const float* feat = (const float*)d_in[7];
    const float* hw   = (const float*)d_in[8];
    const float* fcw  = (const float*)d_in[9];
    const float* fcb  = (const float*)d_in[10];
    float* out = (float*)d_out;
    float* ws  = (float*)d_ws;

    float* At   = ws + WS_AT;
    float* ysum = ws + WS_YSUM;
    unsigned* xmax = (unsigned*)(ws + WS_XMAX);
    int* hist   = (int*)(ws + WS_HIST);
    float* thr  = ws + WS_THR;
    unsigned* mnb = (unsigned*)(ws + WS_MN);
    unsigned* mxb = (unsigned*)(ws + WS_MX);
    float* xp   = ws + WS_XP;
    float* ia   = ws + WS_IA;
    float* xgl  = ws + WS_XGL;
    float* p2   = ws + WS_XP + 20480;

    float* hge = out + GDM_OUT;
    float* p0  = hge;                    // pool scratch in hge region (overwritten by k_hge)

    k_front      <<<2129, 256, 0, stream>>>(x, hw, fcw, xp, ia, At, ws + WS_YSUM);
    k_conv7      <<<dim3(64, 8), 256, 0, stream>>>(xp, convw, ysum);
    k_gl_hist    <<<dim3(256, 8), 256, 0, stream>>>(ia, gdmw, xgl, hist, xmax);
    k_thresholds <<<1, 64, 0, stream>>>(ysum, bng, bnb, bnm, bnv, hist, thr, mnb, mxb);
    k_hv1        <<<dim3(32, 40), 256, 0, stream>>>(xgl, thr, xmax, p0);
    k_hv2s2      <<<dim3(16, 40), 256, 0, stream>>>(p0, p2, mnb, mxb);
    k_norm       <<<640, 256, 0, stream>>>(p2, mnb, mxb, out);
    k_hge        <<<dim3(64, 8), 512, 0, stream>>>(feat, At, fcb, hge);
}